// Round 6
// baseline (158.777 us; speedup 1.0000x reference)
//
#include <hip/hip_runtime.h>
#include <hip/hip_bf16.h>
#include <hip/hip_fp8.h>
#include <math.h>

#define NROW 4096
#define DIM  512
#define M2   8192                     // 2N rows
#define SELF_EXP 7.3890560989306495f  // exp(1/T) = exp(2)
#define NTILE 64                      // M2 / 128
#define NBLK  (NTILE * (NTILE + 1) / 2)   // 2080 upper-triangle tiles (8*260)
#define BK    64                      // K-step (fp8 elements) -> 64 B rows
#define NKS   (DIM / BK)              // 8 K-steps
#define SCL1  0x7F7F7F7F              // E8M0 = 127 -> scale 1.0 (exact)

typedef __attribute__((ext_vector_type(4)))  int   i32x4;
typedef __attribute__((ext_vector_type(8)))  int   i32x8;   // 32 fp8 = 8 VGPRs
typedef __attribute__((ext_vector_type(16))) float f32x16;  // 32x32 C/D

// ---------------------------------------------------------------------------
// Kernel 1: fused row-normalize (x,y -> fp8 e4m3 ns[8192][512]) + positive-
// pair cosine partial (EXACT fp32 path) + rowsum zeroing + out zeroing.
// ---------------------------------------------------------------------------
__global__ __launch_bounds__(256) void norm_pos_kernel(
    const float* __restrict__ x, const float* __restrict__ y,
    unsigned char* __restrict__ ns, float* __restrict__ pospart,
    float* __restrict__ rowsum, float* __restrict__ out)
{
    const int i = blockIdx.x;
    const int t = threadIdx.x;
    const float2 a = ((const float2*)(x + (size_t)i * DIM))[t];
    const float2 b = ((const float2*)(y + (size_t)i * DIM))[t];
    float sx = a.x * a.x + a.y * a.y;
    float sy = b.x * b.x + b.y * b.y;
    float dt = a.x * b.x + a.y * b.y;
    #pragma unroll
    for (int o = 1; o < 64; o <<= 1) {
        sx += __shfl_xor(sx, o);
        sy += __shfl_xor(sy, o);
        dt += __shfl_xor(dt, o);
    }
    __shared__ float rd[12];
    const int wid = t >> 6, lane = t & 63;
    if (lane == 0) { rd[wid] = sx; rd[4 + wid] = sy; rd[8 + wid] = dt; }
    __syncthreads();
    const float SX = rd[0] + rd[1] + rd[2] + rd[3];
    const float SY = rd[4] + rd[5] + rd[6] + rd[7];
    const float D  = rd[8] + rd[9] + rd[10] + rd[11];
    const float rnx = rsqrtf(SX), rny = rsqrtf(SY);

    __hip_fp8_e4m3 qa0(a.x * rnx), qa1(a.y * rnx);
    __hip_fp8_e4m3 qb0(b.x * rny), qb1(b.y * rny);
    uchar2 ua, ub;
    ua.x = (unsigned char)qa0.__x; ua.y = (unsigned char)qa1.__x;
    ub.x = (unsigned char)qb0.__x; ub.y = (unsigned char)qb1.__x;
    ((uchar2*)(void*)(ns + (size_t)i * DIM))[t] = ua;
    ((uchar2*)(void*)(ns + (size_t)(i + NROW) * DIM))[t] = ub;

    if (t == 0) pospart[i] = D * rnx * rny;
    if (t < 2)  rowsum[2 * i + t] = 0.f;
    if (i == 0 && t == 0) out[0] = 0.f;
}

// ---------------------------------------------------------------------------
// Kernel 2: symmetric Gram (fp8 e4m3) via MX-scaled MFMA 32x32x64 (scale=1.0
// exact, 2x the non-scaled fp8 rate, 4 instrs/K-step/wave instead of 32).
// Same verified skeleton: 128x128 tile, BK=64 (64-B rows, byte-identical LDS
// layout/staging/swizzle to the R5 fp8 kernel), 32 KiB dbuf LDS (4 blk/CU),
// counted vmcnt(4) prefetch, both-sides slot swizzle, XCD-chunked blockIdx.
// k-permutation inside a row is harmless: A and B share the instruction's
// (lane,byte)->k map, so it cancels in the symmetric dot product (R5-proven).
// NOTE: __launch_bounds__(256,4) is load-bearing (R3: (256,5) -> spills).
// ---------------------------------------------------------------------------
__device__ __forceinline__ void stage_tiles(
    const char* nsb, char* lA, char* lB, int bi, int bj, int koff, int t)
{
    #pragma unroll
    for (int l = 0; l < 4; ++l) {                 // exactly 4 loads/thread
        const int chunk = l * 256 + t;            // 0..1023 16B chunks
        const int half  = chunk >> 9;             // 0:A 1:B (wave-uniform)
        const int o     = (chunk & 511) * 16;     // byte off within 8 KiB tile
        const int row   = o >> 6;                 // 64 B per LDS row
        const int slot  = (o >> 4) & 3;
        const int src   = (slot ^ ((row >> 1) & 3)) << 4;  // inverse swizzle
        const int grow  = (half ? bj : bi) * 128 + row;
        const char* gsrc = nsb + (size_t)grow * DIM + koff + src;  // 512 B rows
        char* ldst = (half ? lB : lA) + o;        // linear LDS dest
        __builtin_amdgcn_global_load_lds(
            (const __attribute__((address_space(1))) void*)gsrc,
            (__attribute__((address_space(3))) void*)ldst, 16, 0, 0);
    }
}

__device__ __forceinline__ i32x8 ld_frag32(const char* base, int off0, int off1)
{
    const i32x4 lo = *(const i32x4*)(base + off0);
    const i32x4 hi = *(const i32x4*)(base + off1);
    i32x8 v;
    v[0] = lo[0]; v[1] = lo[1]; v[2] = lo[2]; v[3] = lo[3];
    v[4] = hi[0]; v[5] = hi[1]; v[6] = hi[2]; v[7] = hi[3];
    return v;
}

#define BARRIER() do { asm volatile("" ::: "memory");                          \
    __builtin_amdgcn_s_barrier(); asm volatile("" ::: "memory"); } while (0)

__global__ __launch_bounds__(256, 4) void gram_rowsum_kernel(
    const unsigned char* __restrict__ ns, float* __restrict__ rowsum)
{
    __shared__ char lA[2][128 * BK];   // 2 x 8 KiB (fp8)
    __shared__ char lB[2][128 * BK];   // 2 x 8 KiB

    // XCD-chunked swizzle: 2080 % 8 == 0, each XCD gets 260 consecutive idx
    const int raw = blockIdx.x;
    const int idx = (raw & 7) * (NBLK / 8) + (raw >> 3);

    // decode upper-triangle tile index: idx = bj*(bj+1)/2 + bi, bi <= bj
    int bj = (int)floorf((sqrtf(8.0f * (float)idx + 1.0f) - 1.0f) * 0.5f);
    while ((bj + 1) * (bj + 2) / 2 <= idx) ++bj;
    while (bj * (bj + 1) / 2 > idx) --bj;
    const int bi = idx - bj * (bj + 1) / 2;

    const int t = threadIdx.x;
    const int lane = t & 63;
    const int l31  = lane & 31;
    const int wid  = t >> 6;
    const int wr = wid >> 1, wc = wid & 1;   // wave quadrant (64x64)
    const int kw = (lane >> 5) * 32;         // k-byte base within 64-B row

    f32x16 acc[2][2];
    #pragma unroll
    for (int m = 0; m < 2; ++m)
        #pragma unroll
        for (int n = 0; n < 2; ++n)
            acc[m][n] = (f32x16)0.f;

    const char* nsb = (const char*)ns;

    stage_tiles(nsb, lA[0], lB[0], bi, bj, 0, t);

    #pragma unroll
    for (int ks = 0; ks < NKS; ++ks) {
        const int cur = ks & 1;
        if (ks < NKS - 1) {
            // issue next K-step's 4 loads, then wait only for the PREVIOUS 4
            stage_tiles(nsb, lA[cur ^ 1], lB[cur ^ 1], bi, bj, (ks + 1) * BK, t);
            __builtin_amdgcn_sched_barrier(0);   // pin issues above the wait
            asm volatile("s_waitcnt vmcnt(4)" ::: "memory");
        } else {
            asm volatile("s_waitcnt vmcnt(0)" ::: "memory");
        }
        BARRIER();                               // all waves: cur buffer ready

        i32x8 av[2], bv[2];
        #pragma unroll
        for (int m = 0; m < 2; ++m) {
            const int row = wr * 64 + m * 32 + l31;
            const int sw  = ((row >> 1) & 3) << 4;
            const char* base = (const char*)lA[cur] + row * 64;
            av[m] = ld_frag32(base, kw ^ sw, (kw + 16) ^ sw);
        }
        #pragma unroll
        for (int n = 0; n < 2; ++n) {
            const int row = wc * 64 + n * 32 + l31;
            const int sw  = ((row >> 1) & 3) << 4;
            const char* base = (const char*)lB[cur] + row * 64;
            bv[n] = ld_frag32(base, kw ^ sw, (kw + 16) ^ sw);
        }
        // K=64 per MFMA: one MX-scaled instruction per 32x32 subtile
        #pragma unroll
        for (int m = 0; m < 2; ++m)
            #pragma unroll
            for (int n = 0; n < 2; ++n)
                acc[m][n] = __builtin_amdgcn_mfma_scale_f32_32x32x64_f8f6f4(
                    av[m], bv[n], acc[m][n], 0, 0, 0, SCL1, 0, SCL1);

        BARRIER();
    }

    // ---- epilogue: E = exp(2S); row sums always, col sums if off-diagonal --
    #pragma unroll
    for (int m = 0; m < 2; ++m)
        #pragma unroll
        for (int n = 0; n < 2; ++n)
            #pragma unroll
            for (int r = 0; r < 16; ++r)
                acc[m][n][r] = __expf(2.0f * acc[m][n][r]);

    // 32x32 C/D layout: col = lane&31 ; row = (reg&3) + 8*(reg>>2) + 4*(lane>>5)
    #pragma unroll
    for (int m = 0; m < 2; ++m) {
        #pragma unroll
        for (int r = 0; r < 16; ++r) {
            float p = acc[m][0][r] + acc[m][1][r];   // both col-subtiles
            p += __shfl_xor(p, 1);
            p += __shfl_xor(p, 2);
            p += __shfl_xor(p, 4);
            p += __shfl_xor(p, 8);
            p += __shfl_xor(p, 16);
            if (l31 == 0) {
                const int row = bi * 128 + wr * 64 + m * 32 +
                                (r & 3) + 8 * (r >> 2) + 4 * (lane >> 5);
                atomicAdd(&rowsum[row], p);
            }
        }
    }
    if (bi != bj) {
        #pragma unroll
        for (int n = 0; n < 2; ++n) {
            float q = 0.f;
            #pragma unroll
            for (int m = 0; m < 2; ++m)
                #pragma unroll
                for (int r = 0; r < 16; ++r)
                    q += acc[m][n][r];
            q += __shfl_xor(q, 32);     // other 16 rows (lane>>5 half)
            if (lane < 32) {
                const int col = bj * 128 + wc * 64 + n * 32 + l31;
                atomicAdd(&rowsum[col], q);
            }
        }
    }
}

// ---------------------------------------------------------------------------
// Kernel 3: finalize -> loss, parallel (32 blocks, atomicAdd into out)
// ---------------------------------------------------------------------------
__global__ __launch_bounds__(256) void finalize_kernel(
    const float* __restrict__ rowsum, const float* __restrict__ pospart,
    float* __restrict__ out)
{
    const int b = blockIdx.x, t = threadIdx.x;
    float s  = logf(rowsum[b * 256 + t] - SELF_EXP);
    float pp = (t < 128) ? pospart[b * 128 + t] : 0.f;
    #pragma unroll
    for (int o = 1; o < 64; o <<= 1) {
        s  += __shfl_xor(s, o);
        pp += __shfl_xor(pp, o);
    }
    __shared__ float rd[8];
    if ((t & 63) == 0) { rd[t >> 6] = s; rd[4 + (t >> 6)] = pp; }
    __syncthreads();
    if (t == 0) {
        const float ts = rd[0] + rd[1] + rd[2] + rd[3];
        const float tp = rd[4] + rd[5] + rd[6] + rd[7];
        atomicAdd(out, (ts - 4.0f * tp) / (float)M2);
    }
}

// ---------------------------------------------------------------------------
extern "C" void kernel_launch(void* const* d_in, const int* in_sizes, int n_in,
                              void* d_out, int out_size, void* d_ws, size_t ws_size,
                              hipStream_t stream)
{
    const float* x = (const float*)d_in[0];
    const float* y = (const float*)d_in[1];
    float* out = (float*)d_out;

    char* ws = (char*)d_ws;
    unsigned char* ns = (unsigned char*)ws;                   // 4 MiB (fp8)
    float* rowsum  = (float*)(ws + (size_t)4 * 1024 * 1024);  // 32 KiB
    float* pospart = rowsum + M2;                             // 16 KiB

    norm_pos_kernel<<<NROW, 256, 0, stream>>>(x, y, ns, pospart, rowsum, out);

    gram_rowsum_kernel<<<NBLK, 256, 0, stream>>>(ns, rowsum);

    finalize_kernel<<<32, 256, 0, stream>>>(rowsum, pospart, out);
}

// Round 7
// 51.066 us; speedup vs baseline: 3.1092x; 3.1092x over previous
//
#include <hip/hip_runtime.h>
#include <hip/hip_bf16.h>
#include <math.h>

#define NROW 4096
#define DIM  512
#define M2   8192                     // 2N rows
#define SELF_EXP 7.3890560989306495f  // exp(1/T) = exp(2)
#define NTILE 64                      // M2 / 128
#define NBLK  (NTILE * (NTILE + 1) / 2)   // 2080 upper-triangle tiles (8*260)
#define BK    64                      // K-step (int8 elements) -> 64 B rows
#define NKS   (DIM / BK)              // 8 K-steps
#define INV127SQ (1.0f / 16129.0f)    // 1/127^2 dequant scale

typedef __attribute__((ext_vector_type(4))) int   i32x4;    // 16 int8 / i32 C
typedef __attribute__((ext_vector_type(4))) float f32x4;

// ---------------------------------------------------------------------------
// Kernel 1: fused row-normalize (x,y -> int8 q = round(127*v_hat)) + positive-
// pair cosine partial (EXACT fp32 path) + rowsum zeroing + out zeroing.
// ---------------------------------------------------------------------------
__global__ __launch_bounds__(256) void norm_pos_kernel(
    const float* __restrict__ x, const float* __restrict__ y,
    unsigned char* __restrict__ ns, float* __restrict__ pospart,
    float* __restrict__ rowsum, float* __restrict__ out)
{
    const int i = blockIdx.x;
    const int t = threadIdx.x;
    const float2 a = ((const float2*)(x + (size_t)i * DIM))[t];
    const float2 b = ((const float2*)(y + (size_t)i * DIM))[t];
    float sx = a.x * a.x + a.y * a.y;
    float sy = b.x * b.x + b.y * b.y;
    float dt = a.x * b.x + a.y * b.y;
    #pragma unroll
    for (int o = 1; o < 64; o <<= 1) {
        sx += __shfl_xor(sx, o);
        sy += __shfl_xor(sy, o);
        dt += __shfl_xor(dt, o);
    }
    __shared__ float rd[12];
    const int wid = t >> 6, lane = t & 63;
    if (lane == 0) { rd[wid] = sx; rd[4 + wid] = sy; rd[8 + wid] = dt; }
    __syncthreads();
    const float SX = rd[0] + rd[1] + rd[2] + rd[3];
    const float SY = rd[4] + rd[5] + rd[6] + rd[7];
    const float D  = rd[8] + rd[9] + rd[10] + rd[11];
    const float rnx = rsqrtf(SX), rny = rsqrtf(SY);

    // components of a unit vector are in [-1,1] -> q in [-127,127], no clamp
    const int qa0 = __float2int_rn(a.x * rnx * 127.f);
    const int qa1 = __float2int_rn(a.y * rnx * 127.f);
    const int qb0 = __float2int_rn(b.x * rny * 127.f);
    const int qb1 = __float2int_rn(b.y * rny * 127.f);
    uchar2 ua, ub;
    ua.x = (unsigned char)(qa0 & 0xff); ua.y = (unsigned char)(qa1 & 0xff);
    ub.x = (unsigned char)(qb0 & 0xff); ub.y = (unsigned char)(qb1 & 0xff);
    ((uchar2*)(void*)(ns + (size_t)i * DIM))[t] = ua;
    ((uchar2*)(void*)(ns + (size_t)(i + NROW) * DIM))[t] = ub;

    if (t == 0) pospart[i] = D * rnx * rny;
    if (t < 2)  rowsum[2 * i + t] = 0.f;
    if (i == 0 && t == 0) out[0] = 0.f;
}

// ---------------------------------------------------------------------------
// Kernel 2: symmetric Gram (int8) via mfma_i32_16x16x64_i8: K=64 in ONE
// instruction -> 16 MFMA/K-step/wave (R5-fp8 had 32), exact int32 accumulate,
// S = acc/127^2. Register shape IDENTICAL to the verified R5 kernel:
// acc 64 AGPR + 16B fragments (i32x4) -> fits the (256,4) 128-reg cap with
// zero spills (the R3/R6 failure mode). LDS layout/staging/swizzle/ds_read
// addresses byte-identical to R5 (proven conflict-free, 0 conflicts).
// k-permutation inside a row cancels: A and B share the instruction's
// (lane,byte)->k map (R5 hardware-proven, absmax 0.0).
// NOTE: __launch_bounds__(256,4) is load-bearing (R3: (256,5) -> spills;
// R6: mfma_scale's i32x8/f32x16 shape -> spills even at (256,4)).
// ---------------------------------------------------------------------------
__device__ __forceinline__ void stage_tiles(
    const char* nsb, char* lA, char* lB, int bi, int bj, int koff, int t)
{
    #pragma unroll
    for (int l = 0; l < 4; ++l) {                 // exactly 4 loads/thread
        const int chunk = l * 256 + t;            // 0..1023 16B chunks
        const int half  = chunk >> 9;             // 0:A 1:B (wave-uniform)
        const int o     = (chunk & 511) * 16;     // byte off within 8 KiB tile
        const int row   = o >> 6;                 // 64 B per LDS row
        const int slot  = (o >> 4) & 3;
        const int src   = (slot ^ ((row >> 1) & 3)) << 4;  // inverse swizzle
        const int grow  = (half ? bj : bi) * 128 + row;
        const char* gsrc = nsb + (size_t)grow * DIM + koff + src;  // 512 B rows
        char* ldst = (half ? lB : lA) + o;        // linear LDS dest
        __builtin_amdgcn_global_load_lds(
            (const __attribute__((address_space(1))) void*)gsrc,
            (__attribute__((address_space(3))) void*)ldst, 16, 0, 0);
    }
}

#define BARRIER() do { asm volatile("" ::: "memory");                          \
    __builtin_amdgcn_s_barrier(); asm volatile("" ::: "memory"); } while (0)

__global__ __launch_bounds__(256, 4) void gram_rowsum_kernel(
    const unsigned char* __restrict__ ns, float* __restrict__ rowsum)
{
    __shared__ char lA[2][128 * BK];   // 2 x 8 KiB (int8)
    __shared__ char lB[2][128 * BK];   // 2 x 8 KiB

    // XCD-chunked swizzle: 2080 % 8 == 0, each XCD gets 260 consecutive idx
    const int raw = blockIdx.x;
    const int idx = (raw & 7) * (NBLK / 8) + (raw >> 3);

    // decode upper-triangle tile index: idx = bj*(bj+1)/2 + bi, bi <= bj
    int bj = (int)floorf((sqrtf(8.0f * (float)idx + 1.0f) - 1.0f) * 0.5f);
    while ((bj + 1) * (bj + 2) / 2 <= idx) ++bj;
    while (bj * (bj + 1) / 2 > idx) --bj;
    const int bi = idx - bj * (bj + 1) / 2;

    const int t = threadIdx.x;
    const int lane = t & 63;
    const int l15  = lane & 15;
    const int wid  = t >> 6;
    const int wr = wid >> 1, wc = wid & 1;   // wave quadrant (64x64)

    i32x4 acc[4][4];
    #pragma unroll
    for (int m = 0; m < 4; ++m)
        #pragma unroll
        for (int n = 0; n < 4; ++n)
            acc[m][n] = (i32x4)0;

    const char* nsb = (const char*)ns;
    const int kb2 = (lane >> 4) * 16;        // byte offset of 16B k-slot

    stage_tiles(nsb, lA[0], lB[0], bi, bj, 0, t);

    #pragma unroll
    for (int ks = 0; ks < NKS; ++ks) {
        const int cur = ks & 1;
        if (ks < NKS - 1) {
            // issue next K-step's 4 loads, then wait only for the PREVIOUS 4
            stage_tiles(nsb, lA[cur ^ 1], lB[cur ^ 1], bi, bj, (ks + 1) * BK, t);
            __builtin_amdgcn_sched_barrier(0);   // pin issues above the wait
            asm volatile("s_waitcnt vmcnt(4)" ::: "memory");
        } else {
            asm volatile("s_waitcnt vmcnt(0)" ::: "memory");
        }
        BARRIER();                               // all waves: cur buffer ready

        i32x4 av[4], bv[4];
        #pragma unroll
        for (int m = 0; m < 4; ++m) {
            const int row = wr * 64 + m * 16 + l15;
            const int sw  = ((row >> 1) & 3) << 4;
            av[m] = *(const i32x4*)((const char*)lA[cur] + row * 64 + (kb2 ^ sw));
        }
        #pragma unroll
        for (int n = 0; n < 4; ++n) {
            const int row = wc * 64 + n * 16 + l15;
            const int sw  = ((row >> 1) & 3) << 4;
            bv[n] = *(const i32x4*)((const char*)lB[cur] + row * 64 + (kb2 ^ sw));
        }
        // K=64 per step: ONE i8 MFMA per 16x16 subtile
        #pragma unroll
        for (int m = 0; m < 4; ++m)
            #pragma unroll
            for (int n = 0; n < 4; ++n)
                acc[m][n] = __builtin_amdgcn_mfma_i32_16x16x64_i8(
                    av[m], bv[n], acc[m][n], 0, 0, 0);

        BARRIER();
    }

    // ---- epilogue: E = exp(2*acc/127^2); row sums; col sums off-diagonal --
    f32x4 e[4][4];
    #pragma unroll
    for (int m = 0; m < 4; ++m)
        #pragma unroll
        for (int n = 0; n < 4; ++n)
            #pragma unroll
            for (int r = 0; r < 4; ++r)
                e[m][n][r] = __expf((float)acc[m][n][r] * (2.0f * INV127SQ));

    // C/D layout (dtype-independent): row = m*16+(lane>>4)*4+reg ; col = n*16+(lane&15)
    #pragma unroll
    for (int m = 0; m < 4; ++m) {
        #pragma unroll
        for (int reg = 0; reg < 4; ++reg) {
            float p = e[m][0][reg] + e[m][1][reg] + e[m][2][reg] + e[m][3][reg];
            p += __shfl_xor(p, 1);
            p += __shfl_xor(p, 2);
            p += __shfl_xor(p, 4);
            p += __shfl_xor(p, 8);
            if (l15 == 0) {
                const int row = bi * 128 + wr * 64 + m * 16 + (lane >> 4) * 4 + reg;
                atomicAdd(&rowsum[row], p);
            }
        }
    }
    if (bi != bj) {
        #pragma unroll
        for (int n = 0; n < 4; ++n) {
            float p = 0.f;
            #pragma unroll
            for (int m = 0; m < 4; ++m)
                #pragma unroll
                for (int reg = 0; reg < 4; ++reg)
                    p += e[m][n][reg];
            p += __shfl_xor(p, 16);
            p += __shfl_xor(p, 32);
            if (lane < 16) {
                const int col = bj * 128 + wc * 64 + n * 16 + lane;
                atomicAdd(&rowsum[col], p);
            }
        }
    }
}

// ---------------------------------------------------------------------------
// Kernel 3: finalize -> loss, parallel (32 blocks, atomicAdd into out)
// ---------------------------------------------------------------------------
__global__ __launch_bounds__(256) void finalize_kernel(
    const float* __restrict__ rowsum, const float* __restrict__ pospart,
    float* __restrict__ out)
{
    const int b = blockIdx.x, t = threadIdx.x;
    float s  = logf(rowsum[b * 256 + t] - SELF_EXP);
    float pp = (t < 128) ? pospart[b * 128 + t] : 0.f;
    #pragma unroll
    for (int o = 1; o < 64; o <<= 1) {
        s  += __shfl_xor(s, o);
        pp += __shfl_xor(pp, o);
    }
    __shared__ float rd[8];
    if ((t & 63) == 0) { rd[t >> 6] = s; rd[4 + (t >> 6)] = pp; }
    __syncthreads();
    if (t == 0) {
        const float ts = rd[0] + rd[1] + rd[2] + rd[3];
        const float tp = rd[4] + rd[5] + rd[6] + rd[7];
        atomicAdd(out, (ts - 4.0f * tp) / (float)M2);
    }
}

// ---------------------------------------------------------------------------
extern "C" void kernel_launch(void* const* d_in, const int* in_sizes, int n_in,
                              void* d_out, int out_size, void* d_ws, size_t ws_size,
                              hipStream_t stream)
{
    const float* x = (const float*)d_in[0];
    const float* y = (const float*)d_in[1];
    float* out = (float*)d_out;

    char* ws = (char*)d_ws;
    unsigned char* ns = (unsigned char*)ws;                   // 4 MiB (int8)
    float* rowsum  = (float*)(ws + (size_t)4 * 1024 * 1024);  // 32 KiB
    float* pospart = rowsum + M2;                             // 16 KiB

    norm_pos_kernel<<<NROW, 256, 0, stream>>>(x, y, ns, pospart, rowsum, out);

    gram_rowsum_kernel<<<NBLK, 256, 0, stream>>>(ns, rowsum);

    finalize_kernel<<<32, 256, 0, stream>>>(rowsum, pospart, out);
}

// Round 8
// 50.511 us; speedup vs baseline: 3.1434x; 1.0110x over previous
//
#include <hip/hip_runtime.h>
#include <hip/hip_bf16.h>
#include <math.h>

#define NROW 4096
#define DIM  512
#define M2   8192                     // 2N rows
#define SELF_EXP 7.3890560989306495f  // exp(1/T) = exp(2)
#define NTILE 64                      // M2 / 128
#define NBLK  (NTILE * (NTILE + 1) / 2)   // 2080 upper-triangle tiles (8*260)
#define BK    64                      // K-step (int8 elements) -> 64 B rows
#define NKS   (DIM / BK)              // 8 K-steps
#define INV127SQ (1.0f / 16129.0f)    // 1/127^2 dequant scale

typedef __attribute__((ext_vector_type(4))) int   i32x4;    // 16 int8 / i32 C
typedef __attribute__((ext_vector_type(4))) float f32x4;

// ---------------------------------------------------------------------------
// Kernel 1: fused row-normalize (x,y -> int8 q = round(127*v_hat)) + positive-
// pair cosine partial (EXACT fp32 path) + rowsum zeroing + out zeroing.
// float4 loads (16 B/lane, coalescing sweet spot), 2 rows per 256-thr block:
// threads 0-127 -> row 2b, threads 128-255 -> row 2b+1. Wave reduce (each
// wave lies fully inside one row-half) + 2-wave LDS combine per row.
// ---------------------------------------------------------------------------
__global__ __launch_bounds__(256) void norm_pos_kernel(
    const float* __restrict__ x, const float* __restrict__ y,
    unsigned char* __restrict__ ns, float* __restrict__ pospart,
    float* __restrict__ rowsum, float* __restrict__ out)
{
    const int b = blockIdx.x;            // 0..2047
    const int t = threadIdx.x;           // 0..255
    const int h = t >> 7;                // row half within block
    const int u = t & 127;               // lane within row
    const int r = b * 2 + h;             // global row 0..4095

    const float4 a = ((const float4*)(x + (size_t)r * DIM))[u];
    const float4 c = ((const float4*)(y + (size_t)r * DIM))[u];
    float sx = a.x * a.x + a.y * a.y + a.z * a.z + a.w * a.w;
    float sy = c.x * c.x + c.y * c.y + c.z * c.z + c.w * c.w;
    float dt = a.x * c.x + a.y * c.y + a.z * c.z + a.w * c.w;
    #pragma unroll
    for (int o = 1; o < 64; o <<= 1) {
        sx += __shfl_xor(sx, o);
        sy += __shfl_xor(sy, o);
        dt += __shfl_xor(dt, o);
    }
    __shared__ float rd[4][3];
    const int w = t >> 6;                // wave 0..3 (waves 2h,2h+1 = row h)
    if ((t & 63) == 0) { rd[w][0] = sx; rd[w][1] = sy; rd[w][2] = dt; }
    __syncthreads();
    const float SX = rd[2 * h][0] + rd[2 * h + 1][0];
    const float SY = rd[2 * h][1] + rd[2 * h + 1][1];
    const float D  = rd[2 * h][2] + rd[2 * h + 1][2];
    const float rnx = rsqrtf(SX), rny = rsqrtf(SY);

    // unit-vector components in [-1,1] -> q in [-127,127], no clamp needed
    uchar4 qa, qc;
    qa.x = (unsigned char)(__float2int_rn(a.x * rnx * 127.f) & 0xff);
    qa.y = (unsigned char)(__float2int_rn(a.y * rnx * 127.f) & 0xff);
    qa.z = (unsigned char)(__float2int_rn(a.z * rnx * 127.f) & 0xff);
    qa.w = (unsigned char)(__float2int_rn(a.w * rnx * 127.f) & 0xff);
    qc.x = (unsigned char)(__float2int_rn(c.x * rny * 127.f) & 0xff);
    qc.y = (unsigned char)(__float2int_rn(c.y * rny * 127.f) & 0xff);
    qc.z = (unsigned char)(__float2int_rn(c.z * rny * 127.f) & 0xff);
    qc.w = (unsigned char)(__float2int_rn(c.w * rny * 127.f) & 0xff);
    ((uchar4*)(void*)(ns + (size_t)r * DIM))[u] = qa;
    ((uchar4*)(void*)(ns + (size_t)(r + NROW) * DIM))[u] = qc;

    if (u == 0) pospart[r] = D * rnx * rny;
    if (t < 4)  rowsum[4 * b + t] = 0.f;
    if (b == 0 && t == 0) out[0] = 0.f;
}

// ---------------------------------------------------------------------------
// Kernel 2: symmetric Gram (int8) via mfma_i32_16x16x64_i8 — UNCHANGED from
// the R7-verified kernel (passed, absmax 0.0, ~36 us, 0 conflicts, no spill).
// K=64/instruction, exact int32 accumulate, S = acc/127^2. 128x128 tile,
// BK=64, 32 KiB dbuf LDS (4 blk/CU), counted vmcnt(4) prefetch, both-sides
// slot swizzle, XCD-chunked blockIdx. At ~97% of the m97-structure ceiling;
// both 8-phase template ports regressed (R1/R2) -> structure frozen.
// NOTE: __launch_bounds__(256,4) is load-bearing (R3: (256,5) -> spills;
// R6: mfma_scale's i32x8/f32x16 shape -> spills even at (256,4)).
// ---------------------------------------------------------------------------
__device__ __forceinline__ void stage_tiles(
    const char* nsb, char* lA, char* lB, int bi, int bj, int koff, int t)
{
    #pragma unroll
    for (int l = 0; l < 4; ++l) {                 // exactly 4 loads/thread
        const int chunk = l * 256 + t;            // 0..1023 16B chunks
        const int half  = chunk >> 9;             // 0:A 1:B (wave-uniform)
        const int o     = (chunk & 511) * 16;     // byte off within 8 KiB tile
        const int row   = o >> 6;                 // 64 B per LDS row
        const int slot  = (o >> 4) & 3;
        const int src   = (slot ^ ((row >> 1) & 3)) << 4;  // inverse swizzle
        const int grow  = (half ? bj : bi) * 128 + row;
        const char* gsrc = nsb + (size_t)grow * DIM + koff + src;  // 512 B rows
        char* ldst = (half ? lB : lA) + o;        // linear LDS dest
        __builtin_amdgcn_global_load_lds(
            (const __attribute__((address_space(1))) void*)gsrc,
            (__attribute__((address_space(3))) void*)ldst, 16, 0, 0);
    }
}

#define BARRIER() do { asm volatile("" ::: "memory");                          \
    __builtin_amdgcn_s_barrier(); asm volatile("" ::: "memory"); } while (0)

__global__ __launch_bounds__(256, 4) void gram_rowsum_kernel(
    const unsigned char* __restrict__ ns, float* __restrict__ rowsum)
{
    __shared__ char lA[2][128 * BK];   // 2 x 8 KiB (int8)
    __shared__ char lB[2][128 * BK];   // 2 x 8 KiB

    // XCD-chunked swizzle: 2080 % 8 == 0, each XCD gets 260 consecutive idx
    const int raw = blockIdx.x;
    const int idx = (raw & 7) * (NBLK / 8) + (raw >> 3);

    // decode upper-triangle tile index: idx = bj*(bj+1)/2 + bi, bi <= bj
    int bj = (int)floorf((sqrtf(8.0f * (float)idx + 1.0f) - 1.0f) * 0.5f);
    while ((bj + 1) * (bj + 2) / 2 <= idx) ++bj;
    while (bj * (bj + 1) / 2 > idx) --bj;
    const int bi = idx - bj * (bj + 1) / 2;

    const int t = threadIdx.x;
    const int lane = t & 63;
    const int l15  = lane & 15;
    const int wid  = t >> 6;
    const int wr = wid >> 1, wc = wid & 1;   // wave quadrant (64x64)

    i32x4 acc[4][4];
    #pragma unroll
    for (int m = 0; m < 4; ++m)
        #pragma unroll
        for (int n = 0; n < 4; ++n)
            acc[m][n] = (i32x4)0;

    const char* nsb = (const char*)ns;
    const int kb2 = (lane >> 4) * 16;        // byte offset of 16B k-slot

    stage_tiles(nsb, lA[0], lB[0], bi, bj, 0, t);

    #pragma unroll
    for (int ks = 0; ks < NKS; ++ks) {
        const int cur = ks & 1;
        if (ks < NKS - 1) {
            // issue next K-step's 4 loads, then wait only for the PREVIOUS 4
            stage_tiles(nsb, lA[cur ^ 1], lB[cur ^ 1], bi, bj, (ks + 1) * BK, t);
            __builtin_amdgcn_sched_barrier(0);   // pin issues above the wait
            asm volatile("s_waitcnt vmcnt(4)" ::: "memory");
        } else {
            asm volatile("s_waitcnt vmcnt(0)" ::: "memory");
        }
        BARRIER();                               // all waves: cur buffer ready

        i32x4 av[4], bv[4];
        #pragma unroll
        for (int m = 0; m < 4; ++m) {
            const int row = wr * 64 + m * 16 + l15;
            const int sw  = ((row >> 1) & 3) << 4;
            av[m] = *(const i32x4*)((const char*)lA[cur] + row * 64 + (kb2 ^ sw));
        }
        #pragma unroll
        for (int n = 0; n < 4; ++n) {
            const int row = wc * 64 + n * 16 + l15;
            const int sw  = ((row >> 1) & 3) << 4;
            bv[n] = *(const i32x4*)((const char*)lB[cur] + row * 64 + (kb2 ^ sw));
        }
        // K=64 per step: ONE i8 MFMA per 16x16 subtile
        #pragma unroll
        for (int m = 0; m < 4; ++m)
            #pragma unroll
            for (int n = 0; n < 4; ++n)
                acc[m][n] = __builtin_amdgcn_mfma_i32_16x16x64_i8(
                    av[m], bv[n], acc[m][n], 0, 0, 0);

        BARRIER();
    }

    // ---- epilogue: E = exp(2*acc/127^2); row sums; col sums off-diagonal --
    f32x4 e[4][4];
    #pragma unroll
    for (int m = 0; m < 4; ++m)
        #pragma unroll
        for (int n = 0; n < 4; ++n)
            #pragma unroll
            for (int r = 0; r < 4; ++r)
                e[m][n][r] = __expf((float)acc[m][n][r] * (2.0f * INV127SQ));

    // C/D layout (dtype-independent): row = m*16+(lane>>4)*4+reg ; col = n*16+(lane&15)
    #pragma unroll
    for (int m = 0; m < 4; ++m) {
        #pragma unroll
        for (int reg = 0; reg < 4; ++reg) {
            float p = e[m][0][reg] + e[m][1][reg] + e[m][2][reg] + e[m][3][reg];
            p += __shfl_xor(p, 1);
            p += __shfl_xor(p, 2);
            p += __shfl_xor(p, 4);
            p += __shfl_xor(p, 8);
            if (l15 == 0) {
                const int row = bi * 128 + wr * 64 + m * 16 + (lane >> 4) * 4 + reg;
                atomicAdd(&rowsum[row], p);
            }
        }
    }
    if (bi != bj) {
        #pragma unroll
        for (int n = 0; n < 4; ++n) {
            float p = 0.f;
            #pragma unroll
            for (int m = 0; m < 4; ++m)
                #pragma unroll
                for (int reg = 0; reg < 4; ++reg)
                    p += e[m][n][reg];
            p += __shfl_xor(p, 16);
            p += __shfl_xor(p, 32);
            if (lane < 16) {
                const int col = bj * 128 + wc * 64 + n * 16 + lane;
                atomicAdd(&rowsum[col], p);
            }
        }
    }
}

// ---------------------------------------------------------------------------
// Kernel 3: finalize -> loss, parallel (32 blocks, atomicAdd into out)
// ---------------------------------------------------------------------------
__global__ __launch_bounds__(256) void finalize_kernel(
    const float* __restrict__ rowsum, const float* __restrict__ pospart,
    float* __restrict__ out)
{
    const int b = blockIdx.x, t = threadIdx.x;
    float s  = logf(rowsum[b * 256 + t] - SELF_EXP);
    float pp = (t < 128) ? pospart[b * 128 + t] : 0.f;
    #pragma unroll
    for (int o = 1; o < 64; o <<= 1) {
        s  += __shfl_xor(s, o);
        pp += __shfl_xor(pp, o);
    }
    __shared__ float rd[8];
    if ((t & 63) == 0) { rd[t >> 6] = s; rd[4 + (t >> 6)] = pp; }
    __syncthreads();
    if (t == 0) {
        const float ts = rd[0] + rd[1] + rd[2] + rd[3];
        const float tp = rd[4] + rd[5] + rd[6] + rd[7];
        atomicAdd(out, (ts - 4.0f * tp) / (float)M2);
    }
}

// ---------------------------------------------------------------------------
extern "C" void kernel_launch(void* const* d_in, const int* in_sizes, int n_in,
                              void* d_out, int out_size, void* d_ws, size_t ws_size,
                              hipStream_t stream)
{
    const float* x = (const float*)d_in[0];
    const float* y = (const float*)d_in[1];
    float* out = (float*)d_out;

    char* ws = (char*)d_ws;
    unsigned char* ns = (unsigned char*)ws;                   // 4 MiB (int8)
    float* rowsum  = (float*)(ws + (size_t)4 * 1024 * 1024);  // 32 KiB
    float* pospart = rowsum + M2;                             // 16 KiB

    norm_pos_kernel<<<NROW / 2, 256, 0, stream>>>(x, y, ns, pospart, rowsum, out);

    gram_rowsum_kernel<<<NBLK, 256, 0, stream>>>(ns, rowsum);

    finalize_kernel<<<32, 256, 0, stream>>>(rowsum, pospart, out);
}

// Round 9
// 45.994 us; speedup vs baseline: 3.4522x; 1.0982x over previous
//
#include <hip/hip_runtime.h>
#include <hip/hip_bf16.h>
#include <math.h>

#define NROW 4096
#define DIM  512
#define M2   8192                     // 2N rows
#define SELF_EXP 7.3890560989306495f  // exp(1/T) = exp(2)
#define NTILE 64                      // M2 / 128
#define NBLK  (NTILE * (NTILE + 1) / 2)   // 2080 upper-triangle tiles (8*260)
#define BK    64                      // K-step (int8 elements) -> 64 B rows
#define NKS   (DIM / BK)              // 8 K-steps
#define INV127SQ (1.0f / 16129.0f)    // 1/127^2 dequant scale

typedef __attribute__((ext_vector_type(4))) int   i32x4;    // 16 int8 / i32 C
typedef __attribute__((ext_vector_type(4))) float f32x4;

// ---------------------------------------------------------------------------
// Kernel 1: fused row-normalize (x,y -> int8 q = round(127*v_hat)) + positive-
// pair cosine partial (EXACT fp32 path) + rowsum zeroing + out zeroing.
// float4 loads, 2 rows per 256-thr block (R8-verified).
// ---------------------------------------------------------------------------
__global__ __launch_bounds__(256) void norm_pos_kernel(
    const float* __restrict__ x, const float* __restrict__ y,
    unsigned char* __restrict__ ns, float* __restrict__ pospart,
    float* __restrict__ rowsum, float* __restrict__ out)
{
    const int b = blockIdx.x;            // 0..2047
    const int t = threadIdx.x;           // 0..255
    const int h = t >> 7;                // row half within block
    const int u = t & 127;               // lane within row
    const int r = b * 2 + h;             // global row 0..4095

    const float4 a = ((const float4*)(x + (size_t)r * DIM))[u];
    const float4 c = ((const float4*)(y + (size_t)r * DIM))[u];
    float sx = a.x * a.x + a.y * a.y + a.z * a.z + a.w * a.w;
    float sy = c.x * c.x + c.y * c.y + c.z * c.z + c.w * c.w;
    float dt = a.x * c.x + a.y * c.y + a.z * c.z + a.w * c.w;
    #pragma unroll
    for (int o = 1; o < 64; o <<= 1) {
        sx += __shfl_xor(sx, o);
        sy += __shfl_xor(sy, o);
        dt += __shfl_xor(dt, o);
    }
    __shared__ float rd[4][3];
    const int w = t >> 6;                // wave 0..3 (waves 2h,2h+1 = row h)
    if ((t & 63) == 0) { rd[w][0] = sx; rd[w][1] = sy; rd[w][2] = dt; }
    __syncthreads();
    const float SX = rd[2 * h][0] + rd[2 * h + 1][0];
    const float SY = rd[2 * h][1] + rd[2 * h + 1][1];
    const float D  = rd[2 * h][2] + rd[2 * h + 1][2];
    const float rnx = rsqrtf(SX), rny = rsqrtf(SY);

    // unit-vector components in [-1,1] -> q in [-127,127], no clamp needed
    uchar4 qa, qc;
    qa.x = (unsigned char)(__float2int_rn(a.x * rnx * 127.f) & 0xff);
    qa.y = (unsigned char)(__float2int_rn(a.y * rnx * 127.f) & 0xff);
    qa.z = (unsigned char)(__float2int_rn(a.z * rnx * 127.f) & 0xff);
    qa.w = (unsigned char)(__float2int_rn(a.w * rnx * 127.f) & 0xff);
    qc.x = (unsigned char)(__float2int_rn(c.x * rny * 127.f) & 0xff);
    qc.y = (unsigned char)(__float2int_rn(c.y * rny * 127.f) & 0xff);
    qc.z = (unsigned char)(__float2int_rn(c.z * rny * 127.f) & 0xff);
    qc.w = (unsigned char)(__float2int_rn(c.w * rny * 127.f) & 0xff);
    ((uchar4*)(void*)(ns + (size_t)r * DIM))[u] = qa;
    ((uchar4*)(void*)(ns + (size_t)(r + NROW) * DIM))[u] = qc;

    if (u == 0) pospart[r] = D * rnx * rny;
    if (t < 4)  rowsum[4 * b + t] = 0.f;
    if (b == 0 && t == 0) out[0] = 0.f;
}

// ---------------------------------------------------------------------------
// Kernel 2: symmetric Gram (int8, mfma_i32_16x16x64_i8, exact int32 accum).
// R9 change: RING-3 LDS (3 x 16 KiB) + merged single barrier per K-step.
// Old structure: [stage next][vmcnt(4)][BAR][reads/MFMA][BAR] = 2 bar/step.
// New: [vmcnt(4) own stage(kt) done][BAR: all stage(kt) done + all reads of
// buf(kt-1) done][stage(kt+2) -> buf[(kt+2)%3] == buf[(kt-1)%3], safe]
// [ds_read buf[kt]][MFMA] = 1 bar/step, counted vmcnt never 0 until tail.
// 48 KiB -> 3 blocks/CU (12 waves): keeps inter-block overlap (R1/R2 lesson).
// ds_read/stage byte layout within a buffer identical to the proven
// conflict-free both-sides slot swizzle. VGPR shape unchanged (no-spill).
// NOTE: R3: (256,5) VGPR cap -> spills; R6: mfma_scale reg shape -> spills.
// ---------------------------------------------------------------------------
__device__ __forceinline__ void stage_tiles(
    const char* nsb, char* buf, int bi, int bj, int koff, int t)
{
    #pragma unroll
    for (int l = 0; l < 4; ++l) {                 // exactly 4 loads/thread
        const int chunk = l * 256 + t;            // 0..1023 16B chunks
        const int half  = chunk >> 9;             // 0:A 1:B (wave-uniform)
        const int o     = (chunk & 511) * 16;     // byte off within 8 KiB tile
        const int row   = o >> 6;                 // 64 B per LDS row
        const int slot  = (o >> 4) & 3;
        const int src   = (slot ^ ((row >> 1) & 3)) << 4;  // inverse swizzle
        const int grow  = (half ? bj : bi) * 128 + row;
        const char* gsrc = nsb + (size_t)grow * DIM + koff + src;  // 512 B rows
        char* ldst = buf + half * 8192 + o;       // linear LDS dest
        __builtin_amdgcn_global_load_lds(
            (const __attribute__((address_space(1))) void*)gsrc,
            (__attribute__((address_space(3))) void*)ldst, 16, 0, 0);
    }
}

#define BARRIER() do { asm volatile("" ::: "memory");                          \
    __builtin_amdgcn_s_barrier(); asm volatile("" ::: "memory"); } while (0)

__global__ __launch_bounds__(256, 3) void gram_rowsum_kernel(
    const unsigned char* __restrict__ ns, float* __restrict__ rowsum)
{
    __shared__ char ring[3][16384];    // 3 x (A 8 KiB + B 8 KiB)

    // XCD-chunked swizzle: 2080 % 8 == 0, each XCD gets 260 consecutive idx
    const int raw = blockIdx.x;
    const int idx = (raw & 7) * (NBLK / 8) + (raw >> 3);

    // decode upper-triangle tile index: idx = bj*(bj+1)/2 + bi, bi <= bj
    int bj = (int)floorf((sqrtf(8.0f * (float)idx + 1.0f) - 1.0f) * 0.5f);
    while ((bj + 1) * (bj + 2) / 2 <= idx) ++bj;
    while (bj * (bj + 1) / 2 > idx) --bj;
    const int bi = idx - bj * (bj + 1) / 2;

    const int t = threadIdx.x;
    const int lane = t & 63;
    const int l15  = lane & 15;
    const int wid  = t >> 6;
    const int wr = wid >> 1, wc = wid & 1;   // wave quadrant (64x64)

    i32x4 acc[4][4];
    #pragma unroll
    for (int m = 0; m < 4; ++m)
        #pragma unroll
        for (int n = 0; n < 4; ++n)
            acc[m][n] = (i32x4)0;

    const char* nsb = (const char*)ns;
    const int kb2 = (lane >> 4) * 16;        // byte offset of 16B k-slot

    // prologue: stage K-steps 0 and 1
    stage_tiles(nsb, ring[0], bi, bj, 0, t);
    stage_tiles(nsb, ring[1], bi, bj, BK, t);

    #pragma unroll
    for (int ks = 0; ks < NKS; ++ks) {       // fully unrolled: ks%3 is const
        // own stage(ks) complete (stage(ks+1) may stay in flight)
        if (ks < NKS - 1) asm volatile("s_waitcnt vmcnt(4)" ::: "memory");
        else              asm volatile("s_waitcnt vmcnt(0)" ::: "memory");
        BARRIER();   // all waves: stage(ks) done AND buf[(ks-1)%3] reads done

        if (ks + 2 < NKS)
            stage_tiles(nsb, ring[(ks + 2) % 3], bi, bj, (ks + 2) * BK, t);
        __builtin_amdgcn_sched_barrier(0);   // keep stage issue above reads

        const char* A = ring[ks % 3];
        const char* B = ring[ks % 3] + 8192;
        i32x4 av[4], bv[4];
        #pragma unroll
        for (int m = 0; m < 4; ++m) {
            const int row = wr * 64 + m * 16 + l15;
            const int sw  = ((row >> 1) & 3) << 4;
            av[m] = *(const i32x4*)(A + row * 64 + (kb2 ^ sw));
        }
        #pragma unroll
        for (int n = 0; n < 4; ++n) {
            const int row = wc * 64 + n * 16 + l15;
            const int sw  = ((row >> 1) & 3) << 4;
            bv[n] = *(const i32x4*)(B + row * 64 + (kb2 ^ sw));
        }
        // K=64 per step: ONE i8 MFMA per 16x16 subtile
        #pragma unroll
        for (int m = 0; m < 4; ++m)
            #pragma unroll
            for (int n = 0; n < 4; ++n)
                acc[m][n] = __builtin_amdgcn_mfma_i32_16x16x64_i8(
                    av[m], bv[n], acc[m][n], 0, 0, 0);
    }

    // ---- epilogue: E = exp(2*acc/127^2); row sums; col sums off-diagonal --
    f32x4 e[4][4];
    #pragma unroll
    for (int m = 0; m < 4; ++m)
        #pragma unroll
        for (int n = 0; n < 4; ++n)
            #pragma unroll
            for (int r = 0; r < 4; ++r)
                e[m][n][r] = __expf((float)acc[m][n][r] * (2.0f * INV127SQ));

    // C/D layout (dtype-independent): row = m*16+(lane>>4)*4+reg ; col = n*16+(lane&15)
    #pragma unroll
    for (int m = 0; m < 4; ++m) {
        #pragma unroll
        for (int reg = 0; reg < 4; ++reg) {
            float p = e[m][0][reg] + e[m][1][reg] + e[m][2][reg] + e[m][3][reg];
            p += __shfl_xor(p, 1);
            p += __shfl_xor(p, 2);
            p += __shfl_xor(p, 4);
            p += __shfl_xor(p, 8);
            if (l15 == 0) {
                const int row = bi * 128 + wr * 64 + m * 16 + (lane >> 4) * 4 + reg;
                atomicAdd(&rowsum[row], p);
            }
        }
    }
    if (bi != bj) {
        #pragma unroll
        for (int n = 0; n < 4; ++n) {
            float p = 0.f;
            #pragma unroll
            for (int m = 0; m < 4; ++m)
                #pragma unroll
                for (int reg = 0; reg < 4; ++reg)
                    p += e[m][n][reg];
            p += __shfl_xor(p, 16);
            p += __shfl_xor(p, 32);
            if (lane < 16) {
                const int col = bj * 128 + wc * 64 + n * 16 + lane;
                atomicAdd(&rowsum[col], p);
            }
        }
    }
}

// ---------------------------------------------------------------------------
// Kernel 3: finalize -> loss, parallel (32 blocks, atomicAdd into out)
// ---------------------------------------------------------------------------
__global__ __launch_bounds__(256) void finalize_kernel(
    const float* __restrict__ rowsum, const float* __restrict__ pospart,
    float* __restrict__ out)
{
    const int b = blockIdx.x, t = threadIdx.x;
    float s  = logf(rowsum[b * 256 + t] - SELF_EXP);
    float pp = (t < 128) ? pospart[b * 128 + t] : 0.f;
    #pragma unroll
    for (int o = 1; o < 64; o <<= 1) {
        s  += __shfl_xor(s, o);
        pp += __shfl_xor(pp, o);
    }
    __shared__ float rd[8];
    if ((t & 63) == 0) { rd[t >> 6] = s; rd[4 + (t >> 6)] = pp; }
    __syncthreads();
    if (t == 0) {
        const float ts = rd[0] + rd[1] + rd[2] + rd[3];
        const float tp = rd[4] + rd[5] + rd[6] + rd[7];
        atomicAdd(out, (ts - 4.0f * tp) / (float)M2);
    }
}

// ---------------------------------------------------------------------------
extern "C" void kernel_launch(void* const* d_in, const int* in_sizes, int n_in,
                              void* d_out, int out_size, void* d_ws, size_t ws_size,
                              hipStream_t stream)
{
    const float* x = (const float*)d_in[0];
    const float* y = (const float*)d_in[1];
    float* out = (float*)d_out;

    char* ws = (char*)d_ws;
    unsigned char* ns = (unsigned char*)ws;                   // 4 MiB (int8)
    float* rowsum  = (float*)(ws + (size_t)4 * 1024 * 1024);  // 32 KiB
    float* pospart = rowsum + M2;                             // 16 KiB

    norm_pos_kernel<<<NROW / 2, 256, 0, stream>>>(x, y, ns, pospart, rowsum, out);

    gram_rowsum_kernel<<<NBLK, 256, 0, stream>>>(ns, rowsum);

    finalize_kernel<<<32, 256, 0, stream>>>(rowsum, pospart, out);
}